// Round 3
// baseline (447.472 us; speedup 1.0000x reference)
//
#include <hip/hip_runtime.h>
#include <math.h>

// Problem shape (from reference setup_inputs): x is (8, 4096, 2048) fp32, L=25.
#define BB 8
#define HH 4096
#define WW 2048
#define FL 25            // specialized filter length (fast path)
#define NB 16            // van Herk output blocks per tile
#define TH (NB * FL)     // 400 output rows per tile

// Fused morphological closing along H (vertical):
//   xp[k]  = x[clamp(k-(L-1), 0, H-1)]          (edge padding)
//   mx[i]  = max_{k=i..i+L-1} xp[k]
//   out[j] = min_{i=j..j+L-1} mx[i]
// van Herk: for blocks of exactly L, sliding max = combine(suffix-scan of
// block t, prefix-scan of block t+1). Applied twice (max then min), fused,
// fully in registers, one global read + one global write per element (+halo).
__global__ __launch_bounds__(256)
void mmv_kernel(const float* __restrict__ x, const int* __restrict__ pL,
                float* __restrict__ out)
{
    const int Lr = pL[0];

    if (Lr == FL) {
        // ---------------- fast path: L == 25 ----------------
        const int w  = blockIdx.x * blockDim.x + threadIdx.x;   // column
        const int b  = blockIdx.z;
        const int h0 = blockIdx.y * TH;                         // first output row of tile
        if (w >= WW) return;

        const size_t plane = (size_t)HH * WW;
        const float* xc = x   + (size_t)b * plane + w;
        float*       oc = out + (size_t)b * plane + w;

        float Sprev[FL];   // suffix-max of current y-block (carried)
        float SminP[FL];   // suffix-min of previous mx-block (carried)
        float c[FL];       // current y-chunk
        float m[FL];       // emitted mx-block

        // chunk t covers y (= xp) indices [h0 + t*L, h0 + t*L + L)
        for (int t = 0; t < NB + 2; ++t) {
            const int kbase = h0 + t * FL;

            // load chunk (clamped row index implements edge padding)
            #pragma unroll
            for (int j = 0; j < FL; ++j) {
                int r = kbase + j - (FL - 1);
                r = r < 0 ? 0 : (r >= HH ? HH - 1 : r);
                c[j] = xc[(size_t)r * WW];
            }

            if (t >= 1) {
                // emit mx block t-1: m[0]=Sprev[0]; m[j]=max(Sprev[j], prefix(c)[j-1])
                float run = c[0];
                m[0] = Sprev[0];
                #pragma unroll
                for (int j = 1; j < FL; ++j) {
                    m[j] = fmaxf(Sprev[j], run);
                    run  = fmaxf(run, c[j]);
                }
            }

            // suffix-max of c -> Sprev (for next iteration)
            Sprev[FL - 1] = c[FL - 1];
            #pragma unroll
            for (int j = FL - 2; j >= 0; --j) Sprev[j] = fmaxf(c[j], Sprev[j + 1]);

            if (t >= 2) {
                // emit mn block t-2 = min-stage combine(SminP, prefix-min of m)
                const int row = h0 + (t - 2) * FL;
                float run2 = m[0];
                if (row < HH) oc[(size_t)row * WW] = SminP[0];
                #pragma unroll
                for (int j = 1; j < FL; ++j) {
                    float o = fminf(SminP[j], run2);
                    run2    = fminf(run2, m[j]);
                    if (row + j < HH) oc[(size_t)(row + j) * WW] = o;
                }
            }

            if (t >= 1) {
                // suffix-min of m -> SminP (for next iteration)
                SminP[FL - 1] = m[FL - 1];
                #pragma unroll
                for (int j = FL - 2; j >= 0; --j) SminP[j] = fminf(m[j], SminP[j + 1]);
            }
        }
    } else {
        // ---------------- generic fallback (never hit in bench) ----------------
        const size_t total    = (size_t)BB * HH * WW;
        const size_t nthreads = (size_t)gridDim.x * gridDim.y * gridDim.z * blockDim.x;
        const size_t bid = blockIdx.x + (size_t)gridDim.x * (blockIdx.y + (size_t)gridDim.y * blockIdx.z);
        size_t tid = bid * blockDim.x + threadIdx.x;

        if (Lr == 1) {
            // torch L==1 special case: shift up by one, repeat last row
            for (size_t e = tid; e < total; e += nthreads) {
                int w = (int)(e % WW);
                size_t t2 = e / WW;
                int h = (int)(t2 % HH);
                int b = (int)(t2 / HH);
                int hs = (h + 1 < HH) ? h + 1 : HH - 1;
                out[e] = x[((size_t)b * HH + hs) * WW + w];
            }
        } else {
            for (size_t e = tid; e < total; e += nthreads) {
                int w = (int)(e % WW);
                size_t t2 = e / WW;
                int h = (int)(t2 % HH);
                int b = (int)(t2 / HH);
                const float* xc = x + (size_t)b * HH * WW + w;
                float mn = INFINITY;
                for (int i = h; i < h + Lr; ++i) {
                    float mx = -INFINITY;
                    for (int k = i; k < i + Lr; ++k) {
                        int r = k - (Lr - 1);
                        r = r < 0 ? 0 : (r >= HH ? HH - 1 : r);
                        mx = fmaxf(mx, xc[(size_t)r * WW]);
                    }
                    mn = fminf(mn, mx);
                }
                out[e] = mn;
            }
        }
    }
}

extern "C" void kernel_launch(void* const* d_in, const int* in_sizes, int n_in,
                              void* d_out, int out_size, void* d_ws, size_t ws_size,
                              hipStream_t stream) {
    const float* x  = (const float*)d_in[0];
    const int*   pL = (const int*)d_in[1];
    float*       o  = (float*)d_out;

    dim3 block(256, 1, 1);
    dim3 grid(WW / 256, (HH + TH - 1) / TH, BB);   // 8 x 11 x 8 = 704 blocks
    mmv_kernel<<<grid, block, 0, stream>>>(x, pL, o);
}

// Round 4
// 445.027 us; speedup vs baseline: 1.0055x; 1.0055x over previous
//
#include <hip/hip_runtime.h>
#include <math.h>

// x: (8, 4096, 2048) fp32, L=25. Morphological closing along H.
#define BB 8
#define HH 4096
#define WW 2048
#define FL 25              // filter length (fast path)
#define NB 16              // van Herk output blocks per tile
#define TH (NB * FL)       // 400 output rows per tile
#define WB 256             // columns per block
#define CHUNK_SLOTS ((FL * WB) / 4)   // 1600 float4 slots per chunk

// Strategy: cooperative float4 row loads (1 KiB contiguous per wave instr,
// 4 full rows per block step) -> LDS; per-thread register van Herk scan over
// its own LDS column (lane->distinct col = conflict-free); outputs staged in
// LDS and stored cooperatively as contiguous float4 rows.
__global__ __launch_bounds__(256, 3)
void mmv_kernel(const float* __restrict__ x, const int* __restrict__ pL,
                float* __restrict__ out)
{
    const int Lr = pL[0];

    if (Lr == FL) {
        __shared__ float in_s[FL * WB];    // 25 KB
        __shared__ float out_s[FL * WB];   // 25 KB
        const int tid = threadIdx.x;
        const int c0  = blockIdx.x * WB;
        const int b   = blockIdx.z;
        const int h0  = blockIdx.y * TH;
        const size_t plane = (size_t)HH * WW;
        const float* xb = x   + (size_t)b * plane + c0;
        float*       ob = out + (size_t)b * plane + c0;

        float m[FL];       // emitted mx-block (registers)
        float Sprev[FL];   // carried suffix-max of current chunk
        float SminP[FL];   // carried suffix-min of previous mx-block

        for (int t = 0; t < NB + 2; ++t) {
            const int kbase = h0 + t * FL;

            // ---- cooperative load: xp rows kbase..kbase+24 (clamped) ----
            #pragma unroll
            for (int it = 0; it < 7; ++it) {
                int s = it * 256 + tid;
                if (s < CHUNK_SLOTS) {
                    int j  = s >> 6;        // row within chunk (wave = 1 row)
                    int c4 = s & 63;        // float4 slot within row
                    int r  = kbase + j - (FL - 1);
                    r = r < 0 ? 0 : (r >= HH ? HH - 1 : r);
                    const float4 v = *reinterpret_cast<const float4*>(
                        xb + (size_t)r * WW + 4 * c4);
                    *reinterpret_cast<float4*>(&in_s[j * WB + 4 * c4]) = v;
                }
            }
            __syncthreads();

            // ---- per-thread van Herk scan on column `tid` ----
            if (t >= 1) {
                // emit mx block t-1: m[j] = max(Sprev[j], prefix(c)[j-1])
                float run = in_s[0 * WB + tid];
                m[0] = Sprev[0];
                #pragma unroll
                for (int j = 1; j < FL; ++j) {
                    m[j] = fmaxf(Sprev[j], run);
                    run  = fmaxf(run, in_s[j * WB + tid]);
                }
            }
            // suffix-max of current chunk -> Sprev
            Sprev[FL - 1] = in_s[(FL - 1) * WB + tid];
            #pragma unroll
            for (int j = FL - 2; j >= 0; --j)
                Sprev[j] = fmaxf(in_s[j * WB + tid], Sprev[j + 1]);

            if (t >= 2) {
                // emit mn block t-2 into out_s: min-combine(SminP, prefix-min(m))
                float run2 = m[0];
                out_s[0 * WB + tid] = SminP[0];
                #pragma unroll
                for (int j = 1; j < FL; ++j) {
                    out_s[j * WB + tid] = fminf(SminP[j], run2);
                    run2 = fminf(run2, m[j]);
                }
            }
            if (t >= 1) {
                // suffix-min of m -> SminP
                SminP[FL - 1] = m[FL - 1];
                #pragma unroll
                for (int j = FL - 2; j >= 0; --j)
                    SminP[j] = fminf(m[j], SminP[j + 1]);
            }
            __syncthreads();

            // ---- cooperative store: output rows h0+(t-2)*25 .. +24 ----
            if (t >= 2) {
                const int rbase = h0 + (t - 2) * FL;
                #pragma unroll
                for (int it = 0; it < 7; ++it) {
                    int s = it * 256 + tid;
                    if (s < CHUNK_SLOTS) {
                        int j   = s >> 6;
                        int c4  = s & 63;
                        int row = rbase + j;
                        if (row < HH) {
                            float4 v = *reinterpret_cast<float4*>(&out_s[j * WB + 4 * c4]);
                            *reinterpret_cast<float4*>(ob + (size_t)row * WW + 4 * c4) = v;
                        }
                    }
                }
            }
            // next loop's first __syncthreads (after coop-load) orders
            // store-reads(t) vs scan-writes(t+1) on out_s; in_s writes(t+1)
            // vs scan-reads(t) are ordered by the barrier above.
        }
    } else {
        // ---------------- generic fallback (never hit in bench) ----------------
        const size_t total    = (size_t)BB * HH * WW;
        const size_t nthreads = (size_t)gridDim.x * gridDim.y * gridDim.z * blockDim.x;
        const size_t bid = blockIdx.x + (size_t)gridDim.x * (blockIdx.y + (size_t)gridDim.y * blockIdx.z);
        size_t tid = bid * blockDim.x + threadIdx.x;

        if (Lr == 1) {
            for (size_t e = tid; e < total; e += nthreads) {
                int w = (int)(e % WW);
                size_t t2 = e / WW;
                int h = (int)(t2 % HH);
                int b = (int)(t2 / HH);
                int hs = (h + 1 < HH) ? h + 1 : HH - 1;
                out[e] = x[((size_t)b * HH + hs) * WW + w];
            }
        } else {
            for (size_t e = tid; e < total; e += nthreads) {
                int w = (int)(e % WW);
                size_t t2 = e / WW;
                int h = (int)(t2 % HH);
                int b = (int)(t2 / HH);
                const float* xc = x + (size_t)b * HH * WW + w;
                float mn = INFINITY;
                for (int i = h; i < h + Lr; ++i) {
                    float mx = -INFINITY;
                    for (int k = i; k < i + Lr; ++k) {
                        int r = k - (Lr - 1);
                        r = r < 0 ? 0 : (r >= HH ? HH - 1 : r);
                        mx = fmaxf(mx, xc[(size_t)r * WW]);
                    }
                    mn = fminf(mn, mx);
                }
                out[e] = mn;
            }
        }
    }
}

extern "C" void kernel_launch(void* const* d_in, const int* in_sizes, int n_in,
                              void* d_out, int out_size, void* d_ws, size_t ws_size,
                              hipStream_t stream) {
    const float* x  = (const float*)d_in[0];
    const int*   pL = (const int*)d_in[1];
    float*       o  = (float*)d_out;

    dim3 block(256, 1, 1);
    dim3 grid(WW / WB, (HH + TH - 1) / TH, BB);   // 8 x 11 x 8 = 704 blocks
    mmv_kernel<<<grid, block, 0, stream>>>(x, pL, o);
}